// Round 3
// baseline (336.389 us; speedup 1.0000x reference)
//
#include <hip/hip_runtime.h>
#include <hip/hip_fp16.h>
#include <hip/hip_fp8.h>
#include <math.h>

#define N_NODES 50000
#define N_EDGES 1200000
#define N_GRAPHS 128
#define D_IN 32
#define D_H 64
#define D_OUT 10
#define ELL_CAP 64

#define EPS 1e-7f
#define MAX_NORM (1.0f - 1e-5f)
// atanh(MAX_NORM): logmap0(proj(expmap0(m))) == m * min(1, TCLIP/||m||)
#define TCLIP 6.1030335f
#define T8SCALE 16.0f            // fp8 table pre-scale (folded into mean div)

// ---- atomic-free ELL build: counting partition ----
#define HB 512                               // partition blocks (chunks)
#define CHUNK ((N_EDGES + HB - 1) / HB)      // 2344 edges per chunk
#define NBUCK ((N_NODES + 63) / 64)          // 782 buckets of 64 nodes

typedef _Float16 half8 __attribute__((ext_vector_type(8)));
typedef float float4v __attribute__((ext_vector_type(4)));
typedef unsigned int uint2v __attribute__((ext_vector_type(2)));

// ---------------- wave helpers ----------------

__device__ __forceinline__ float wave_reduce_sum(float v) {
    #pragma unroll
    for (int off = 32; off > 0; off >>= 1)
        v += __shfl_xor(v, off, 64);
    return v;
}

// logmap0(proj(expmap0(m))) collapsed to a norm clip (one reduction).
__device__ __forceinline__ float epl_clip64(float m) {
    float n = sqrtf(wave_reduce_sum(m * m));
    float sc = (n > TCLIP) ? (TCLIP / n) : 1.0f;
    return m * sc;
}

// two packed OCP e4m3 bytes -> two floats (gfx950 HW cvt)
__device__ __forceinline__ float2 fp8x2_to_f2(ushort v) {
    __hip_fp8_e4m3 a, b;
    a.__x = (__hip_fp8_storage_t)(v & 0xff);
    b.__x = (__hip_fp8_storage_t)(v >> 8);
    return make_float2((float)a, (float)b);
}

// ---------------- kernels ----------------

// Partition pass: blocks [0,HB) bucket-sort their edge chunk locally
// (LDS histogram + scan + LDS-atomic rank; all global writes coalesced
// into the block's own window -> full write combining, NO global atomics).
// Blocks [HB..): tangent0 = fp16(clip(x)) (unchanged u0 computation).
__global__ void partsort_kernel(const int* __restrict__ src, const int* __restrict__ dst,
                                unsigned* __restrict__ sorted, int* __restrict__ rowOffs,
                                const float* __restrict__ x, __half* __restrict__ u0) {
    __shared__ int hist[1024];   // NBUCK=782 padded to 4*256
    __shared__ int wsum[256];
    if (blockIdx.x >= HB) {
        int gid = (blockIdx.x - HB) * 256 + threadIdx.x;
        int node = gid >> 6;
        int lane = gid & 63;
        if (node >= N_NODES) return;
        float m = (lane < D_IN) ? __builtin_nontemporal_load(x + node * D_IN + lane) : 0.0f;
        float t = epl_clip64(m);
        if (lane < D_IN) u0[node * D_IN + lane] = __float2half(t);
        return;
    }
    int i = blockIdx.x;
    int e0 = i * CHUNK;
    int e1 = min(e0 + CHUNK, N_EDGES);

    for (int t = threadIdx.x; t < 1024; t += 256) hist[t] = 0;
    __syncthreads();
    // pass 1: bucket histogram (LDS atomics only)
    for (int e = e0 + threadIdx.x; e < e1; e += 256) {
        int d = dst[e];
        d = min(max(d, 0), N_NODES - 1);
        atomicAdd(&hist[d >> 6], 1);
    }
    __syncthreads();
    // exclusive scan of hist[0..1023]: 4 elems/thread + block scan of sums
    int t = threadIdx.x;
    int a0 = hist[4 * t], a1 = hist[4 * t + 1], a2 = hist[4 * t + 2], a3 = hist[4 * t + 3];
    int s01 = a0 + a1;
    int s = s01 + a2 + a3;
    wsum[t] = s;
    __syncthreads();
    for (int off = 1; off < 256; off <<= 1) {
        int v = (t >= off) ? wsum[t - off] : 0;
        __syncthreads();
        wsum[t] += v;
        __syncthreads();
    }
    int base = wsum[t] - s;      // exclusive prefix of this thread's 4
    hist[4 * t]     = base;
    hist[4 * t + 1] = base + a0;
    hist[4 * t + 2] = base + s01;
    hist[4 * t + 3] = base + s01 + a2;
    __syncthreads();
    // publish per-(chunk,bucket) offsets; row-major -> coalesced writes.
    for (int jj = threadIdx.x; jj <= NBUCK; jj += 256)
        __builtin_nontemporal_store(hist[jj], rowOffs + i * (NBUCK + 1) + jj);
    __syncthreads();
    // pass 2: rank via LDS atomic on the scanned cursors, write packed edge
    // into this block's own CHUNK-sized window.
    for (int e = e0 + threadIdx.x; e < e1; e += 256) {
        int s_ = src[e];
        int d  = dst[e];
        s_ = min(max(s_, 0), N_NODES - 1);
        d  = min(max(d,  0), N_NODES - 1);
        int pos = atomicAdd(&hist[d >> 6], 1);
        __builtin_nontemporal_store(((unsigned)d << 16) | (unsigned)s_,
                                    sorted + (size_t)i * CHUNK + pos);
    }
}

// ELL build: one block per 64-node bucket. Gathers this bucket's runs from
// all HB chunk windows; ranks with LDS atomics; ELL writes land in the
// block's own contiguous 16KB region. Exact deg falls out of the counters.
__global__ void ellbuild_kernel(const unsigned* __restrict__ sorted, const int* __restrict__ rowOffs,
                                int* __restrict__ deg, ushort* __restrict__ ell) {
    __shared__ int cnt[64];
    int j = blockIdx.x;
    if (threadIdx.x < 64) cnt[threadIdx.x] = 0;
    __syncthreads();
    for (int i = threadIdx.x; i < HB; i += 256) {
        int b0 = __builtin_nontemporal_load(rowOffs + i * (NBUCK + 1) + j);
        int b1 = __builtin_nontemporal_load(rowOffs + i * (NBUCK + 1) + j + 1);
        const unsigned* sp = sorted + (size_t)i * CHUNK;
        for (int e = b0; e < b1; ++e) {
            unsigned p = __builtin_nontemporal_load(sp + e);
            int dl = (int)(p >> 16) & 63;
            int pos = atomicAdd(&cnt[dl], 1);
            if (pos < ELL_CAP)
                ell[(size_t)((j << 6) + dl) * ELL_CAP + pos] = (ushort)(p & 0xffffu);
        }
    }
    __syncthreads();
    int node = (j << 6) + threadIdx.x;
    if (threadIdx.x < 64 && node < N_NODES) deg[node] = cnt[threadIdx.x];
}

// Repack W (f32 [K,64]) into B-fragment order for mfma_f32_16x16x32_f16.
template <int K>
__global__ void repack_kernel(const float* __restrict__ W, __half* __restrict__ Whf) {
    const int NF = K / 32;
    int idx = blockIdx.x * 256 + threadIdx.x;
    if (idx >= 4 * NF * 64 * 8) return;
    int j = idx & 7;
    int lane = (idx >> 3) & 63;
    int f = (idx >> 9) % NF;
    int jb = (idx >> 9) / NF;
    int k = f * 32 + ((lane >> 4) * 8) + j;
    int n = jb * 16 + (lane & 15);
    Whf[idx] = __float2half(W[k * 64 + n]);
}

// LAYER 1 pass A: gather-mean of u0 rows (32-dim fp16 = 64B = 1 line/edge,
// L2-resident). 8 lanes per row, uint2/lane. Indices loaded DIRECTLY per
// batch (8-lane broadcast load) -- no ELL row staging, no bpermute chain:
// each gather pipelines behind its own tiny index load.
__global__ void meangather_kernel(const __half* __restrict__ u0, const int* __restrict__ deg,
                                  const ushort* __restrict__ ell, __half* __restrict__ m0) {
    int widx = threadIdx.x >> 6;
    int lane = threadIdx.x & 63;
    int node = blockIdx.x * 4 + widx;
    if (node >= N_NODES) return;
    int g = lane >> 3;          // edge group 0..7
    int d8 = lane & 7;          // dim slice: halfs d8*4 .. d8*4+3
    int dt = deg[node];
    int d = min(dt, ELL_CAP);
    const ushort* erow = ell + (size_t)node * ELL_CAP;
    const char* base = (const char*)u0;

    // issue all index loads up-front (unconditional; tail slots clamped)
    int sidx[8];
    #pragma unroll
    for (int i = 0; i < 8; ++i)
        sidx[i] = (int)__builtin_nontemporal_load(erow + i * 8 + g);

    uint2v v[8];
    #pragma unroll
    for (int i = 0; i < 8; ++i)
        if (i * 8 < d) {        // wave-uniform
            int s = min(sidx[i], N_NODES - 1);
            v[i] = *(const uint2v*)(base + ((size_t)s << 6) + (d8 << 3));
        }

    float a0 = 0.f, a1 = 0.f, a2 = 0.f, a3 = 0.f;
    #pragma unroll
    for (int i = 0; i < 8; ++i) {
        if (i * 8 < d) {
            float w = ((i * 8 + g) < d) ? 1.0f : 0.0f;
            uint lo_ = v[i][0], hi_ = v[i][1];
            float2 f0 = __half22float2(*reinterpret_cast<const __half2*>(&lo_));
            float2 f1 = __half22float2(*reinterpret_cast<const __half2*>(&hi_));
            a0 = fmaf(f0.x, w, a0);
            a1 = fmaf(f0.y, w, a1);
            a2 = fmaf(f1.x, w, a2);
            a3 = fmaf(f1.y, w, a3);
        }
    }
    // reduce across the 8 edge-groups (lane bits 3..5)
    #pragma unroll
    for (int off = 8; off <= 32; off <<= 1) {
        a0 += __shfl_xor(a0, off, 64);
        a1 += __shfl_xor(a1, off, 64);
        a2 += __shfl_xor(a2, off, 64);
        a3 += __shfl_xor(a3, off, 64);
    }
    float inv = 1.0f / fmaxf((float)dt, 1.0f);
    if (g == 0) {
        __half2 h0 = __floats2half2_rn(a0 * inv, a1 * inv);
        __half2 h1 = __floats2half2_rn(a2 * inv, a3 * inv);
        uint2v pk;
        pk[0] = *reinterpret_cast<uint*>(&h0);
        pk[1] = *reinterpret_cast<uint*>(&h1);
        __builtin_nontemporal_store(pk, (uint2v*)((char*)m0 + ((size_t)node << 6) + (d8 << 3)));
    }
}

// LAYER 1 pass B: u1 = clip(lrelu(m0@W1 + b1)), deg==0 -> 0.
__global__ void gemmepi_kernel(const __half* __restrict__ m0, const __half* __restrict__ Whf,
                               const float* __restrict__ b, const int* __restrict__ deg,
                               __half* __restrict__ uout) {
    int gw = blockIdx.x * 4 + (threadIdx.x >> 6);
    int lane = threadIdx.x & 63;
    int node0 = gw * 16;
    if (node0 >= N_NODES) return;
    int m = lane & 15, quad = lane >> 4;

    half8 a = __builtin_nontemporal_load(
        (const half8*)(m0 + (size_t)(node0 + m) * 32 + quad * 8));
    float h[4][4];   // [jb][r]
    #pragma unroll
    for (int jb = 0; jb < 4; ++jb) {
        float4v acc = {0.f, 0.f, 0.f, 0.f};
        half8 bb = ((const half8*)Whf)[jb * 64 + lane];
        acc = __builtin_amdgcn_mfma_f32_16x16x32_f16(a, bb, acc, 0, 0, 0);
        float bias = b[jb * 16 + m];
        #pragma unroll
        for (int r = 0; r < 4; ++r) h[jb][r] = acc[r] + bias;
    }
    #pragma unroll
    for (int r = 0; r < 4; ++r) {
        int node = node0 + quad * 4 + r;   // C/D: col=lane&15, row=quad*4+reg
        int dt = deg[node];
        float nr = 0.f;
        #pragma unroll
        for (int jb = 0; jb < 4; ++jb) {
            float v = (dt == 0) ? 0.f : h[jb][r];
            v = (v >= 0.f) ? v : 0.2f * v;   // leaky_relu (layer 1)
            h[jb][r] = v;
            nr += v * v;
        }
        nr += __shfl_xor(nr, 1, 64); nr += __shfl_xor(nr, 2, 64);
        nr += __shfl_xor(nr, 4, 64); nr += __shfl_xor(nr, 8, 64);
        float n = sqrtf(nr);
        float sc = (n > TCLIP) ? (TCLIP / n) : 1.0f;
        #pragma unroll
        for (int jb = 0; jb < 4; ++jb)
            uout[node * 64 + jb * 16 + m] = __float2half(h[jb][r] * sc);
    }
}

// t[N,64] fp8 e4m3 (x16 scale) = u[N,K] fp16 @ W + b via MFMA (layers 2,3).
template <int K>
__global__ void gemm_kernel(const __half* __restrict__ u, const __half* __restrict__ Whf,
                            const float* __restrict__ b, __hip_fp8_e4m3* __restrict__ t8) {
    const int NF = K / 32;
    int gw = blockIdx.x * 4 + (threadIdx.x >> 6);
    int lane = threadIdx.x & 63;
    int jb = gw & 3;
    int tile = gw >> 2;
    int node0 = tile * 16;
    if (node0 >= N_NODES) return;
    int m = lane & 15, quad = lane >> 4;

    float4v acc = {0.f, 0.f, 0.f, 0.f};
    const half8* bfr = (const half8*)Whf + (size_t)(jb * NF) * 64 + lane;
    #pragma unroll
    for (int f = 0; f < NF; ++f) {
        half8 a = __builtin_nontemporal_load(
            (const half8*)(u + (size_t)(node0 + m) * K + f * 32 + quad * 8));
        half8 bb = bfr[f * 64];
        acc = __builtin_amdgcn_mfma_f32_16x16x32_f16(a, bb, acc, 0, 0, 0);
    }
    int j = jb * 16 + m;
    float bias = b[j];
    #pragma unroll
    for (int r = 0; r < 4; ++r) {
        int node = node0 + quad * 4 + r;
        t8[node * 64 + j] = __hip_fp8_e4m3((acc[r] + bias) * T8SCALE);
    }
}

// Gather-mean over ELL (fp8 rows, 64B = 1 line/edge). 8 lanes per row,
// uint2/lane. Direct per-batch index loads (no bpermute chain). Streaming
// accesses non-temporal so the t8 table stays L2-resident.
template <int ACT, int POOL>
__global__ void agg_kernel(const __hip_fp8_e4m3* __restrict__ t8, const int* __restrict__ deg,
                           const ushort* __restrict__ ell, __half* __restrict__ uout,
                           const int* __restrict__ batch, float* __restrict__ pooled,
                           float* __restrict__ cntg) {
    __shared__ float rs[4][64];
    __shared__ int gs[4];
    int widx = threadIdx.x >> 6;
    int lane = threadIdx.x & 63;
    int node = blockIdx.x * 4 + widx;
    if (node >= N_NODES) return;   // never taken when POOL (50000 % 4 == 0)
    int g = lane >> 3;          // edge group 0..7
    int d8 = lane & 7;          // dim slice: dims d8*8 .. d8*8+7
    int dt = deg[node];
    int d = min(dt, ELL_CAP);
    const ushort* erow = ell + (size_t)node * ELL_CAP;
    const char* base = (const char*)t8;

    int sidx[8];
    #pragma unroll
    for (int i = 0; i < 8; ++i)
        sidx[i] = (int)__builtin_nontemporal_load(erow + i * 8 + g);

    uint2v v[8];
    #pragma unroll
    for (int i = 0; i < 8; ++i)
        if (i * 8 < d) {        // wave-uniform
            int s = min(sidx[i], N_NODES - 1);
            v[i] = *(const uint2v*)(base + ((size_t)s << 6) + (d8 << 3));
        }

    float acc[8] = {0.f, 0.f, 0.f, 0.f, 0.f, 0.f, 0.f, 0.f};
    #pragma unroll
    for (int i = 0; i < 8; ++i) {
        if (i * 8 < d) {
            float w = ((i * 8 + g) < d) ? 1.0f : 0.0f;
            uint lo_ = v[i][0], hi_ = v[i][1];
            float2 f0 = fp8x2_to_f2((ushort)(lo_ & 0xffffu));
            float2 f1 = fp8x2_to_f2((ushort)(lo_ >> 16));
            float2 f2 = fp8x2_to_f2((ushort)(hi_ & 0xffffu));
            float2 f3 = fp8x2_to_f2((ushort)(hi_ >> 16));
            acc[0] = fmaf(f0.x, w, acc[0]);
            acc[1] = fmaf(f0.y, w, acc[1]);
            acc[2] = fmaf(f1.x, w, acc[2]);
            acc[3] = fmaf(f1.y, w, acc[3]);
            acc[4] = fmaf(f2.x, w, acc[4]);
            acc[5] = fmaf(f2.y, w, acc[5]);
            acc[6] = fmaf(f3.x, w, acc[6]);
            acc[7] = fmaf(f3.y, w, acc[7]);
        }
    }
    // reduce across the 8 edge-groups (lane bits 3..5)
    #pragma unroll
    for (int j = 0; j < 8; ++j) {
        acc[j] += __shfl_xor(acc[j], 8, 64);
        acc[j] += __shfl_xor(acc[j], 16, 64);
        acc[j] += __shfl_xor(acc[j], 32, 64);
    }

    // mean; the /T8SCALE undoes the fp8 table pre-scale (free)
    float inv = 1.0f / (T8SCALE * fmaxf((float)dt, 1.0f));
    float val[8];
    float nr = 0.f;
    #pragma unroll
    for (int j = 0; j < 8; ++j) {
        float m = acc[j] * inv;
        if (ACT) m = (m >= 0.f) ? m : 0.2f * m;
        val[j] = m;
        nr = fmaf(m, m, nr);
    }
    // norm: sum the 8 dim-slices (lane bits 0..2)
    nr += __shfl_xor(nr, 1, 64);
    nr += __shfl_xor(nr, 2, 64);
    nr += __shfl_xor(nr, 4, 64);
    float n = sqrtf(nr);
    float sc = (n > TCLIP) ? (TCLIP / n) : 1.0f;
    #pragma unroll
    for (int j = 0; j < 8; ++j) val[j] *= sc;

    if (POOL) {
        int gi = min(max(batch[node], 0), N_GRAPHS - 1);
        if (g == 0) {
            #pragma unroll
            for (int j = 0; j < 8; ++j) rs[widx][d8 * 8 + j] = val[j];
        }
        if (lane == 0) gs[widx] = gi;
        __syncthreads();
        int g0 = gs[0], g1 = gs[1], g2 = gs[2], g3 = gs[3];
        bool uni = (g0 == g1) && (g1 == g2) && (g2 == g3);
        if (uni) {
            if (widx == 0) {
                float sum = rs[0][lane] + rs[1][lane] + rs[2][lane] + rs[3][lane];
                atomicAdd(&pooled[g0 * 64 + lane], sum);
                if (lane == 0) atomicAdd(&cntg[g0], 4.0f);
            }
        } else {
            if (g == 0) {
                #pragma unroll
                for (int j = 0; j < 8; ++j)
                    atomicAdd(&pooled[gi * 64 + d8 * 8 + j], val[j]);
            }
            if (lane == 0) atomicAdd(&cntg[gi], 1.0f);
        }
    } else {
        if (g == 0) {
            half8 hv;
            #pragma unroll
            for (int j = 0; j < 8; ++j) hv[j] = (_Float16)val[j];
            __builtin_nontemporal_store(hv,
                (half8*)((char*)uout + ((size_t)node << 7) + (d8 << 4)));
        }
    }
}

// final head: mean -> clip -> @Wl + bl -> expmap0 -> proj (literal output)
__global__ void head_kernel(const float* __restrict__ pooled, const float* __restrict__ cntg,
                            const float* __restrict__ Wl, const float* __restrict__ bl,
                            float* __restrict__ out) {
    int g = blockIdx.x;
    int lane = threadIdx.x;
    float m = pooled[g * 64 + lane] / fmaxf(cntg[g], 1.0f);
    float z = epl_clip64(m);
    float acc = 0.0f;
    #pragma unroll
    for (int k = 0; k < 64; ++k) {
        float zk = __shfl(z, k, 64);
        if (lane < D_OUT) acc = fmaf(zk, Wl[k * D_OUT + lane], acc);
    }
    float o = (lane < D_OUT) ? (acc + bl[lane]) : 0.0f;
    float n = fmaxf(sqrtf(wave_reduce_sum(o * o)), EPS);
    float v = tanhf(n) * o / n;
    float nv = fmaxf(sqrtf(wave_reduce_sum(v * v)), EPS);
    if (nv > MAX_NORM) v = v * (MAX_NORM / nv);
    if (lane < D_OUT) out[g * D_OUT + lane] = v;
}

// ---------------- launch ----------------

extern "C" void kernel_launch(void* const* d_in, const int* in_sizes, int n_in,
                              void* d_out, int out_size, void* d_ws, size_t ws_size,
                              hipStream_t stream) {
    const float* x   = (const float*)d_in[0];
    const int* edge  = (const int*)d_in[1];
    const int* batch = (const int*)d_in[2];
    const float* W1  = (const float*)d_in[3];
    const float* b1  = (const float*)d_in[4];
    const float* W2  = (const float*)d_in[5];
    const float* b2  = (const float*)d_in[6];
    const float* W3  = (const float*)d_in[7];
    const float* b3  = (const float*)d_in[8];
    const float* Wl  = (const float*)d_in[9];
    const float* bl  = (const float*)d_in[10];
    float* out = (float*)d_out;

    const int N = N_NODES, E = N_EDGES, G = N_GRAPHS;
    const int* src = edge;
    const int* dst = edge + E;

    // ws layout: [deg][pooled][cntg][ell][u0h N*32 h][u1h N*64 h][u2h N*64 h]
    //            [t8 N*64 fp8][m0h N*32 h][Wh1][Wh2][Wh3]
    // transient build aliases: sorted (4.8MB) -> u2h region (6.4MB),
    //                          rowOffs (1.6MB) -> t8 region (3.2MB).
    char* ws = (char*)d_ws;
    int*    deg    = (int*)ws;
    float*  pooled = (float*)(deg + N);
    float*  cntg   = pooled + (size_t)G * 64;
    ushort* ell    = (ushort*)(cntg + G);
    __half* u0h    = (__half*)(ell + (size_t)N * ELL_CAP);
    __half* u1h    = u0h + (size_t)N * 32;
    __half* u2h    = u1h + (size_t)N * 64;
    __hip_fp8_e4m3* t8 = (__hip_fp8_e4m3*)(u2h + (size_t)N * 64);
    __half* m0h    = (__half*)((char*)t8 + (size_t)N * 64);
    __half* Wh1    = m0h + (size_t)N * 32;    // 2048
    __half* Wh2    = Wh1 + 2048;              // 4096
    __half* Wh3    = Wh2 + 4096;              // 4096

    unsigned* sortedbuf = (unsigned*)u2h;     // HB*CHUNK u32 = 4.8MB <= 6.4MB
    int*      rowOffs   = (int*)t8;           // HB*(NBUCK+1) = 1.6MB <= 3.2MB

    // deg is fully overwritten by ellbuild; only pooling accumulators need 0.
    hipMemsetAsync(pooled, 0, ((size_t)G * 64 + G) * 4, stream);

    int blocksN64 = (N * 64 + 255) / 256;   // one wave per node, 4 per block
    int blocksG   = 3125;                   // layers 2,3 gemm (jb split)
    int blocksT   = (3125 + 3) / 4;         // gemmepi: one wave per 16-node tile

    repack_kernel<32><<<8,  256, 0, stream>>>(W1, Wh1);
    repack_kernel<64><<<16, 256, 0, stream>>>(W2, Wh2);
    repack_kernel<64><<<16, 256, 0, stream>>>(W3, Wh3);

    // atomic-free ELL build: local bucket-partition, then per-bucket build
    partsort_kernel<<<HB + blocksN64, 256, 0, stream>>>(src, dst, sortedbuf, rowOffs, x, u0h);
    ellbuild_kernel<<<NBUCK, 256, 0, stream>>>(sortedbuf, rowOffs, deg, ell);

    // layer 1: gather-mean u0 (L2-resident, 1 line/edge) -> MFMA+epi
    meangather_kernel<<<blocksN64, 256, 0, stream>>>(u0h, deg, ell, m0h);
    gemmepi_kernel<<<blocksT, 256, 0, stream>>>(m0h, Wh1, b1, deg, u1h);

    // layer 2: fp8 table (1 line/edge gather)
    gemm_kernel<64><<<blocksG, 256, 0, stream>>>(u1h, Wh2, b2, t8);
    agg_kernel<1, 0><<<blocksN64, 256, 0, stream>>>(t8, deg, ell, u2h, nullptr, nullptr, nullptr);
    // layer 3 (no act) + LDS-combined pooling
    gemm_kernel<64><<<blocksG, 256, 0, stream>>>(u2h, Wh3, b3, t8);
    agg_kernel<0, 1><<<blocksN64, 256, 0, stream>>>(t8, deg, ell, nullptr, batch, pooled, cntg);

    head_kernel<<<G, 64, 0, stream>>>(pooled, cntg, Wl, bl, out);
}

// Round 9
// 262.647 us; speedup vs baseline: 1.2808x; 1.2808x over previous
//
#include <hip/hip_runtime.h>
#include <hip/hip_fp16.h>
#include <hip/hip_fp8.h>
#include <math.h>

#define N_NODES 50000
#define N_EDGES 1200000
#define N_GRAPHS 128
#define D_IN 32
#define D_H 64
#define D_OUT 10
#define ELL_CAP 64

#define EPS 1e-7f
#define MAX_NORM (1.0f - 1e-5f)
// atanh(MAX_NORM): logmap0(proj(expmap0(m))) == m * min(1, TCLIP/||m||)
#define TCLIP 6.1030335f
#define T8SCALE 16.0f            // fp8 table pre-scale (folded into mean div)

// ---- atomic-free ELL build: counting partition ----
#define HB 512                               // partition blocks (chunks)
#define CHUNK ((N_EDGES + HB - 1) / HB)      // 2344 edges per chunk
#define NBUCK ((N_NODES + 63) / 64)          // 782 buckets of 64 nodes

// persistent-wave grid for the gather kernels
#define GPB 2048                             // blocks; 8192 waves

typedef _Float16 half8 __attribute__((ext_vector_type(8)));
typedef float float4v __attribute__((ext_vector_type(4)));
typedef unsigned int uint2v __attribute__((ext_vector_type(2)));

// ---------------- wave helpers ----------------

__device__ __forceinline__ float wave_reduce_sum(float v) {
    #pragma unroll
    for (int off = 32; off > 0; off >>= 1)
        v += __shfl_xor(v, off, 64);
    return v;
}

// logmap0(proj(expmap0(m))) collapsed to a norm clip (one reduction).
__device__ __forceinline__ float epl_clip64(float m) {
    float n = sqrtf(wave_reduce_sum(m * m));
    float sc = (n > TCLIP) ? (TCLIP / n) : 1.0f;
    return m * sc;
}

// two packed OCP e4m3 bytes -> two floats (gfx950 HW cvt)
__device__ __forceinline__ float2 fp8x2_to_f2(ushort v) {
    __hip_fp8_e4m3 a, b;
    a.__x = (__hip_fp8_storage_t)(v & 0xff);
    b.__x = (__hip_fp8_storage_t)(v >> 8);
    return make_float2((float)a, (float)b);
}

// ---------------- kernels ----------------

// Partition pass: blocks [0,HB) bucket-sort their edge chunk locally
// (LDS histogram + scan + LDS-atomic rank; all global writes coalesced
// into the block's own window -> full write combining, NO global atomics).
// Blocks [HB..): tangent0 = fp16(clip(x)) (unchanged u0 computation).
__global__ void partsort_kernel(const int* __restrict__ src, const int* __restrict__ dst,
                                unsigned* __restrict__ sorted, int* __restrict__ rowOffs,
                                const float* __restrict__ x, __half* __restrict__ u0) {
    __shared__ int hist[1024];   // NBUCK=782 padded to 4*256
    __shared__ int wsum[256];
    if (blockIdx.x >= HB) {
        int gid = (blockIdx.x - HB) * 256 + threadIdx.x;
        int node = gid >> 6;
        int lane = gid & 63;
        if (node >= N_NODES) return;
        float m = (lane < D_IN) ? x[node * D_IN + lane] : 0.0f;
        float t = epl_clip64(m);
        if (lane < D_IN) u0[node * D_IN + lane] = __float2half(t);
        return;
    }
    int i = blockIdx.x;
    int e0 = i * CHUNK;
    int e1 = min(e0 + CHUNK, N_EDGES);

    for (int t = threadIdx.x; t < 1024; t += 256) hist[t] = 0;
    __syncthreads();
    // pass 1: bucket histogram (LDS atomics only)
    for (int e = e0 + threadIdx.x; e < e1; e += 256) {
        int d = dst[e];
        d = min(max(d, 0), N_NODES - 1);
        atomicAdd(&hist[d >> 6], 1);
    }
    __syncthreads();
    // exclusive scan of hist[0..1023]: 4 elems/thread + block scan of sums
    int t = threadIdx.x;
    int a0 = hist[4 * t], a1 = hist[4 * t + 1], a2 = hist[4 * t + 2], a3 = hist[4 * t + 3];
    int s01 = a0 + a1;
    int s = s01 + a2 + a3;
    wsum[t] = s;
    __syncthreads();
    for (int off = 1; off < 256; off <<= 1) {
        int v = (t >= off) ? wsum[t - off] : 0;
        __syncthreads();
        wsum[t] += v;
        __syncthreads();
    }
    int base = wsum[t] - s;      // exclusive prefix of this thread's 4
    hist[4 * t]     = base;
    hist[4 * t + 1] = base + a0;
    hist[4 * t + 2] = base + s01;
    hist[4 * t + 3] = base + s01 + a2;
    __syncthreads();
    // publish per-(chunk,bucket) offsets; row-major -> coalesced writes.
    for (int jj = threadIdx.x; jj <= NBUCK; jj += 256)
        rowOffs[i * (NBUCK + 1) + jj] = hist[jj];
    __syncthreads();
    // pass 2: rank via LDS atomic on the scanned cursors, write packed edge
    // into this block's own CHUNK-sized window.
    for (int e = e0 + threadIdx.x; e < e1; e += 256) {
        int s_ = src[e];
        int d  = dst[e];
        s_ = min(max(s_, 0), N_NODES - 1);
        d  = min(max(d,  0), N_NODES - 1);
        int pos = atomicAdd(&hist[d >> 6], 1);
        sorted[(size_t)i * CHUNK + pos] = ((unsigned)d << 16) | (unsigned)s_;
    }
}

// ELL build: one block per 64-node bucket. Gathers this bucket's runs from
// all HB chunk windows; ranks with LDS atomics; ELL writes land in the
// block's own contiguous 16KB region. Exact deg falls out of the counters.
__global__ void ellbuild_kernel(const unsigned* __restrict__ sorted, const int* __restrict__ rowOffs,
                                int* __restrict__ deg, ushort* __restrict__ ell) {
    __shared__ int cnt[64];
    int j = blockIdx.x;
    if (threadIdx.x < 64) cnt[threadIdx.x] = 0;
    __syncthreads();
    for (int i = threadIdx.x; i < HB; i += 256) {
        int b0 = rowOffs[i * (NBUCK + 1) + j];
        int b1 = rowOffs[i * (NBUCK + 1) + j + 1];
        const unsigned* sp = sorted + (size_t)i * CHUNK;
        for (int e = b0; e < b1; ++e) {
            unsigned p = sp[e];
            int dl = (int)(p >> 16) & 63;
            int pos = atomicAdd(&cnt[dl], 1);
            if (pos < ELL_CAP)
                ell[(size_t)((j << 6) + dl) * ELL_CAP + pos] = (ushort)(p & 0xffffu);
        }
    }
    __syncthreads();
    int node = (j << 6) + threadIdx.x;
    if (threadIdx.x < 64 && node < N_NODES) deg[node] = cnt[threadIdx.x];
}

// Repack W (f32 [K,64]) into B-fragment order for mfma_f32_16x16x32_f16.
template <int K>
__global__ void repack_kernel(const float* __restrict__ W, __half* __restrict__ Whf) {
    const int NF = K / 32;
    int idx = blockIdx.x * 256 + threadIdx.x;
    if (idx >= 4 * NF * 64 * 8) return;
    int j = idx & 7;
    int lane = (idx >> 3) & 63;
    int f = (idx >> 9) % NF;
    int jb = (idx >> 9) / NF;
    int k = f * 32 + ((lane >> 4) * 8) + j;
    int n = jb * 16 + (lane & 15);
    Whf[idx] = __float2half(W[k * 64 + n]);
}

// LAYER 1 pass A: gather-mean of u0 rows (32-dim fp16 = 64B = 1 line/edge,
// L2-resident). Persistent waves, one node per wave per iteration, with
// NEXT node's deg+indices prefetched while current gathers are in flight.
__global__ void meangather_kernel(const __half* __restrict__ u0, const int* __restrict__ deg,
                                  const ushort* __restrict__ ell, __half* __restrict__ m0) {
    int wid = (blockIdx.x * 256 + threadIdx.x) >> 6;
    int lane = threadIdx.x & 63;
    int nw = gridDim.x * 4;
    int g = lane >> 3;          // edge group 0..7
    int d8 = lane & 7;          // dim slice: halfs d8*4 .. d8*4+3
    const char* base = (const char*)u0;

    int node = wid;
    int dt = 0;
    int sidx[8] = {0, 0, 0, 0, 0, 0, 0, 0};
    if (node < N_NODES) {
        dt = deg[node];
        const ushort* er = ell + (size_t)node * ELL_CAP;
        #pragma unroll
        for (int i = 0; i < 8; ++i) sidx[i] = (int)er[i * 8 + g];
    }

    while (node < N_NODES) {
        int d = min(dt, ELL_CAP);
        // issue current node's gathers
        uint2v v[8];
        #pragma unroll
        for (int i = 0; i < 8; ++i)
            if (i * 8 < d) {    // wave-uniform
                int s = min(sidx[i], N_NODES - 1);
                v[i] = *(const uint2v*)(base + ((size_t)s << 6) + (d8 << 3));
            }
        // prefetch next node's deg + indices (independent of v)
        int nnode = node + nw;
        int dt_n = 0;
        int sx_n[8] = {0, 0, 0, 0, 0, 0, 0, 0};
        if (nnode < N_NODES) {
            dt_n = deg[nnode];
            const ushort* er = ell + (size_t)nnode * ELL_CAP;
            #pragma unroll
            for (int i = 0; i < 8; ++i) sx_n[i] = (int)er[i * 8 + g];
        }
        // accumulate current
        float a0 = 0.f, a1 = 0.f, a2 = 0.f, a3 = 0.f;
        #pragma unroll
        for (int i = 0; i < 8; ++i) {
            if (i * 8 < d) {
                float w = ((i * 8 + g) < d) ? 1.0f : 0.0f;
                uint lo_ = v[i][0], hi_ = v[i][1];
                float2 f0 = __half22float2(*reinterpret_cast<const __half2*>(&lo_));
                float2 f1 = __half22float2(*reinterpret_cast<const __half2*>(&hi_));
                a0 = fmaf(f0.x, w, a0);
                a1 = fmaf(f0.y, w, a1);
                a2 = fmaf(f1.x, w, a2);
                a3 = fmaf(f1.y, w, a3);
            }
        }
        #pragma unroll
        for (int off = 8; off <= 32; off <<= 1) {
            a0 += __shfl_xor(a0, off, 64);
            a1 += __shfl_xor(a1, off, 64);
            a2 += __shfl_xor(a2, off, 64);
            a3 += __shfl_xor(a3, off, 64);
        }
        float inv = 1.0f / fmaxf((float)dt, 1.0f);
        if (g == 0) {
            __half2 h0 = __floats2half2_rn(a0 * inv, a1 * inv);
            __half2 h1 = __floats2half2_rn(a2 * inv, a3 * inv);
            uint2v pk;
            pk[0] = *reinterpret_cast<uint*>(&h0);
            pk[1] = *reinterpret_cast<uint*>(&h1);
            *(uint2v*)((char*)m0 + ((size_t)node << 6) + (d8 << 3)) = pk;
        }
        // rotate pipeline
        node = nnode;
        dt = dt_n;
        #pragma unroll
        for (int i = 0; i < 8; ++i) sidx[i] = sx_n[i];
    }
}

// LAYER 1 pass B: u1 = clip(lrelu(m0@W1 + b1)), deg==0 -> 0.
__global__ void gemmepi_kernel(const __half* __restrict__ m0, const __half* __restrict__ Whf,
                               const float* __restrict__ b, const int* __restrict__ deg,
                               __half* __restrict__ uout) {
    int gw = blockIdx.x * 4 + (threadIdx.x >> 6);
    int lane = threadIdx.x & 63;
    int node0 = gw * 16;
    if (node0 >= N_NODES) return;
    int m = lane & 15, quad = lane >> 4;

    half8 a = *(const half8*)(m0 + (size_t)(node0 + m) * 32 + quad * 8);
    float h[4][4];   // [jb][r]
    #pragma unroll
    for (int jb = 0; jb < 4; ++jb) {
        float4v acc = {0.f, 0.f, 0.f, 0.f};
        half8 bb = ((const half8*)Whf)[jb * 64 + lane];
        acc = __builtin_amdgcn_mfma_f32_16x16x32_f16(a, bb, acc, 0, 0, 0);
        float bias = b[jb * 16 + m];
        #pragma unroll
        for (int r = 0; r < 4; ++r) h[jb][r] = acc[r] + bias;
    }
    #pragma unroll
    for (int r = 0; r < 4; ++r) {
        int node = node0 + quad * 4 + r;   // C/D: col=lane&15, row=quad*4+reg
        int dt = deg[node];
        float nr = 0.f;
        #pragma unroll
        for (int jb = 0; jb < 4; ++jb) {
            float v = (dt == 0) ? 0.f : h[jb][r];
            v = (v >= 0.f) ? v : 0.2f * v;   // leaky_relu (layer 1)
            h[jb][r] = v;
            nr += v * v;
        }
        nr += __shfl_xor(nr, 1, 64); nr += __shfl_xor(nr, 2, 64);
        nr += __shfl_xor(nr, 4, 64); nr += __shfl_xor(nr, 8, 64);
        float n = sqrtf(nr);
        float sc = (n > TCLIP) ? (TCLIP / n) : 1.0f;
        #pragma unroll
        for (int jb = 0; jb < 4; ++jb)
            uout[node * 64 + jb * 16 + m] = __float2half(h[jb][r] * sc);
    }
}

// t[N,64] fp8 e4m3 (x16 scale) = u[N,K] fp16 @ W + b via MFMA (layers 2,3).
template <int K>
__global__ void gemm_kernel(const __half* __restrict__ u, const __half* __restrict__ Whf,
                            const float* __restrict__ b, __hip_fp8_e4m3* __restrict__ t8) {
    const int NF = K / 32;
    int gw = blockIdx.x * 4 + (threadIdx.x >> 6);
    int lane = threadIdx.x & 63;
    int jb = gw & 3;
    int tile = gw >> 2;
    int node0 = tile * 16;
    if (node0 >= N_NODES) return;
    int m = lane & 15, quad = lane >> 4;

    float4v acc = {0.f, 0.f, 0.f, 0.f};
    const half8* bfr = (const half8*)Whf + (size_t)(jb * NF) * 64 + lane;
    #pragma unroll
    for (int f = 0; f < NF; ++f) {
        half8 a = *(const half8*)(u + (size_t)(node0 + m) * K + f * 32 + quad * 8);
        half8 bb = bfr[f * 64];
        acc = __builtin_amdgcn_mfma_f32_16x16x32_f16(a, bb, acc, 0, 0, 0);
    }
    int j = jb * 16 + m;
    float bias = b[j];
    #pragma unroll
    for (int r = 0; r < 4; ++r) {
        int node = node0 + quad * 4 + r;
        t8[node * 64 + j] = __hip_fp8_e4m3((acc[r] + bias) * T8SCALE);
    }
}

// Gather-mean over ELL (fp8 rows, 64B = 1 line/edge). Persistent waves,
// one node/wave/iteration, next node's deg+indices prefetched under the
// in-flight gathers. act -> norm-clip -> fp16 store, or (POOL) block LDS
// combine + 1 atomic burst per block. (layers 2,3)
template <int ACT, int POOL>
__global__ void agg_kernel(const __hip_fp8_e4m3* __restrict__ t8, const int* __restrict__ deg,
                           const ushort* __restrict__ ell, __half* __restrict__ uout,
                           const int* __restrict__ batch, float* __restrict__ pooled,
                           float* __restrict__ cntg) {
    __shared__ float rs[4][64];
    __shared__ int gs[4];
    int widx = threadIdx.x >> 6;
    int lane = threadIdx.x & 63;
    int wid = blockIdx.x * 4 + widx;
    int nw = gridDim.x * 4;
    int g = lane >> 3;          // edge group 0..7
    int d8 = lane & 7;          // dim slice: dims d8*8 .. d8*8+7
    const char* base = (const char*)t8;

    int iters = (N_NODES + nw - 1) / nw;   // uniform across block (sync safety)
    int node = wid;
    int dt = 0;
    int sidx[8] = {0, 0, 0, 0, 0, 0, 0, 0};
    if (node < N_NODES) {
        dt = deg[node];
        const ushort* er = ell + (size_t)node * ELL_CAP;
        #pragma unroll
        for (int i = 0; i < 8; ++i) sidx[i] = (int)er[i * 8 + g];
    }

    for (int it = 0; it < iters; ++it) {
        bool active = node < N_NODES;
        int d = active ? min(dt, ELL_CAP) : 0;
        // issue current node's gathers
        uint2v v[8];
        #pragma unroll
        for (int i = 0; i < 8; ++i)
            if (i * 8 < d) {    // wave-uniform
                int s = min(sidx[i], N_NODES - 1);
                v[i] = *(const uint2v*)(base + ((size_t)s << 6) + (d8 << 3));
            }
        // prefetch next node's deg + indices (independent of v)
        int nnode = node + nw;
        int dt_n = 0;
        int sx_n[8] = {0, 0, 0, 0, 0, 0, 0, 0};
        if (nnode < N_NODES) {
            dt_n = deg[nnode];
            const ushort* er = ell + (size_t)nnode * ELL_CAP;
            #pragma unroll
            for (int i = 0; i < 8; ++i) sx_n[i] = (int)er[i * 8 + g];
        }
        // accumulate current
        float acc[8] = {0.f, 0.f, 0.f, 0.f, 0.f, 0.f, 0.f, 0.f};
        #pragma unroll
        for (int i = 0; i < 8; ++i) {
            if (i * 8 < d) {
                float w = ((i * 8 + g) < d) ? 1.0f : 0.0f;
                uint lo_ = v[i][0], hi_ = v[i][1];
                float2 f0 = fp8x2_to_f2((ushort)(lo_ & 0xffffu));
                float2 f1 = fp8x2_to_f2((ushort)(lo_ >> 16));
                float2 f2 = fp8x2_to_f2((ushort)(hi_ & 0xffffu));
                float2 f3 = fp8x2_to_f2((ushort)(hi_ >> 16));
                acc[0] = fmaf(f0.x, w, acc[0]);
                acc[1] = fmaf(f0.y, w, acc[1]);
                acc[2] = fmaf(f1.x, w, acc[2]);
                acc[3] = fmaf(f1.y, w, acc[3]);
                acc[4] = fmaf(f2.x, w, acc[4]);
                acc[5] = fmaf(f2.y, w, acc[5]);
                acc[6] = fmaf(f3.x, w, acc[6]);
                acc[7] = fmaf(f3.y, w, acc[7]);
            }
        }
        #pragma unroll
        for (int j = 0; j < 8; ++j) {
            acc[j] += __shfl_xor(acc[j], 8, 64);
            acc[j] += __shfl_xor(acc[j], 16, 64);
            acc[j] += __shfl_xor(acc[j], 32, 64);
        }

        // mean; the /T8SCALE undoes the fp8 table pre-scale (free)
        float inv = 1.0f / (T8SCALE * fmaxf((float)dt, 1.0f));
        float val[8];
        float nr = 0.f;
        #pragma unroll
        for (int j = 0; j < 8; ++j) {
            float m = acc[j] * inv;
            if (ACT) m = (m >= 0.f) ? m : 0.2f * m;
            val[j] = m;
            nr = fmaf(m, m, nr);
        }
        nr += __shfl_xor(nr, 1, 64);
        nr += __shfl_xor(nr, 2, 64);
        nr += __shfl_xor(nr, 4, 64);
        float n = sqrtf(nr);
        float sc = (n > TCLIP) ? (TCLIP / n) : 1.0f;
        #pragma unroll
        for (int j = 0; j < 8; ++j) val[j] *= sc;

        if (POOL) {
            int gi = active ? min(max(batch[node], 0), N_GRAPHS - 1) : -1;
            if (g == 0 && active) {
                #pragma unroll
                for (int j = 0; j < 8; ++j) rs[widx][d8 * 8 + j] = val[j];
            }
            if (lane == 0) gs[widx] = gi;
            __syncthreads();
            int g0 = gs[0], g1 = gs[1], g2 = gs[2], g3 = gs[3];
            bool uni = (g0 >= 0) && (g0 == g1) && (g1 == g2) && (g2 == g3);
            if (uni) {
                if (widx == 0) {
                    float sum = rs[0][lane] + rs[1][lane] + rs[2][lane] + rs[3][lane];
                    atomicAdd(&pooled[g0 * 64 + lane], sum);
                    if (lane == 0) atomicAdd(&cntg[g0], 4.0f);
                }
            } else if (active) {
                if (g == 0) {
                    #pragma unroll
                    for (int j = 0; j < 8; ++j)
                        atomicAdd(&pooled[gi * 64 + d8 * 8 + j], val[j]);
                }
                if (lane == 0) atomicAdd(&cntg[gi], 1.0f);
            }
            __syncthreads();   // rs/gs reused next iteration
        } else {
            if (g == 0 && active) {
                half8 hv;
                #pragma unroll
                for (int j = 0; j < 8; ++j) hv[j] = (_Float16)val[j];
                *(half8*)((char*)uout + ((size_t)node << 7) + (d8 << 4)) = hv;
            }
        }
        // rotate pipeline
        node = nnode;
        dt = dt_n;
        #pragma unroll
        for (int i = 0; i < 8; ++i) sidx[i] = sx_n[i];
    }
}

// final head: mean -> clip -> @Wl + bl -> expmap0 -> proj (literal output)
__global__ void head_kernel(const float* __restrict__ pooled, const float* __restrict__ cntg,
                            const float* __restrict__ Wl, const float* __restrict__ bl,
                            float* __restrict__ out) {
    int g = blockIdx.x;
    int lane = threadIdx.x;
    float m = pooled[g * 64 + lane] / fmaxf(cntg[g], 1.0f);
    float z = epl_clip64(m);
    float acc = 0.0f;
    #pragma unroll
    for (int k = 0; k < 64; ++k) {
        float zk = __shfl(z, k, 64);
        if (lane < D_OUT) acc = fmaf(zk, Wl[k * D_OUT + lane], acc);
    }
    float o = (lane < D_OUT) ? (acc + bl[lane]) : 0.0f;
    float n = fmaxf(sqrtf(wave_reduce_sum(o * o)), EPS);
    float v = tanhf(n) * o / n;
    float nv = fmaxf(sqrtf(wave_reduce_sum(v * v)), EPS);
    if (nv > MAX_NORM) v = v * (MAX_NORM / nv);
    if (lane < D_OUT) out[g * D_OUT + lane] = v;
}

// ---------------- launch ----------------

extern "C" void kernel_launch(void* const* d_in, const int* in_sizes, int n_in,
                              void* d_out, int out_size, void* d_ws, size_t ws_size,
                              hipStream_t stream) {
    const float* x   = (const float*)d_in[0];
    const int* edge  = (const int*)d_in[1];
    const int* batch = (const int*)d_in[2];
    const float* W1  = (const float*)d_in[3];
    const float* b1  = (const float*)d_in[4];
    const float* W2  = (const float*)d_in[5];
    const float* b2  = (const float*)d_in[6];
    const float* W3  = (const float*)d_in[7];
    const float* b3  = (const float*)d_in[8];
    const float* Wl  = (const float*)d_in[9];
    const float* bl  = (const float*)d_in[10];
    float* out = (float*)d_out;

    const int N = N_NODES, E = N_EDGES, G = N_GRAPHS;
    const int* src = edge;
    const int* dst = edge + E;

    // ws layout: [deg][pooled][cntg][ell][u0h N*32 h][u1h N*64 h][u2h N*64 h]
    //            [t8 N*64 fp8][m0h N*32 h][Wh1][Wh2][Wh3]
    // transient build aliases: sorted (4.8MB) -> u2h region (6.4MB),
    //                          rowOffs (1.6MB) -> t8 region (3.2MB).
    char* ws = (char*)d_ws;
    int*    deg    = (int*)ws;
    float*  pooled = (float*)(deg + N);
    float*  cntg   = pooled + (size_t)G * 64;
    ushort* ell    = (ushort*)(cntg + G);
    __half* u0h    = (__half*)(ell + (size_t)N * ELL_CAP);
    __half* u1h    = u0h + (size_t)N * 32;
    __half* u2h    = u1h + (size_t)N * 64;
    __hip_fp8_e4m3* t8 = (__hip_fp8_e4m3*)(u2h + (size_t)N * 64);
    __half* m0h    = (__half*)((char*)t8 + (size_t)N * 64);
    __half* Wh1    = m0h + (size_t)N * 32;    // 2048
    __half* Wh2    = Wh1 + 2048;              // 4096
    __half* Wh3    = Wh2 + 4096;              // 4096

    unsigned* sortedbuf = (unsigned*)u2h;     // HB*CHUNK u32 = 4.8MB <= 6.4MB
    int*      rowOffs   = (int*)t8;           // HB*(NBUCK+1) = 1.6MB <= 3.2MB

    // deg is fully overwritten by ellbuild; only pooling accumulators need 0.
    hipMemsetAsync(pooled, 0, ((size_t)G * 64 + G) * 4, stream);

    int blocksN64 = (N * 64 + 255) / 256;   // u0 tangent map part of partsort
    int blocksG   = 3125;                   // layers 2,3 gemm (jb split)
    int blocksT   = (3125 + 3) / 4;         // gemmepi: one wave per 16-node tile

    repack_kernel<32><<<8,  256, 0, stream>>>(W1, Wh1);
    repack_kernel<64><<<16, 256, 0, stream>>>(W2, Wh2);
    repack_kernel<64><<<16, 256, 0, stream>>>(W3, Wh3);

    // atomic-free ELL build: local bucket-partition, then per-bucket build
    partsort_kernel<<<HB + blocksN64, 256, 0, stream>>>(src, dst, sortedbuf, rowOffs, x, u0h);
    ellbuild_kernel<<<NBUCK, 256, 0, stream>>>(sortedbuf, rowOffs, deg, ell);

    // layer 1: gather-mean u0 (L2-resident, 1 line/edge) -> MFMA+epi
    meangather_kernel<<<GPB, 256, 0, stream>>>(u0h, deg, ell, m0h);
    gemmepi_kernel<<<blocksT, 256, 0, stream>>>(m0h, Wh1, b1, deg, u1h);

    // layer 2: fp8 table (1 line/edge gather)
    gemm_kernel<64><<<blocksG, 256, 0, stream>>>(u1h, Wh2, b2, t8);
    agg_kernel<1, 0><<<GPB, 256, 0, stream>>>(t8, deg, ell, u2h, nullptr, nullptr, nullptr);
    // layer 3 (no act) + LDS-combined pooling
    gemm_kernel<64><<<blocksG, 256, 0, stream>>>(u2h, Wh3, b3, t8);
    agg_kernel<0, 1><<<GPB, 256, 0, stream>>>(t8, deg, ell, nullptr, batch, pooled, cntg);

    head_kernel<<<G, 64, 0, stream>>>(pooled, cntg, Wl, bl, out);
}